// Round 16
// baseline (84.964 us; speedup 1.0000x reference)
//
#include <hip/hip_runtime.h>
#include <hip/hip_bf16.h>

typedef unsigned short u16;
typedef unsigned int u32;
typedef __attribute__((ext_vector_type(8))) short bf16x8;
typedef __attribute__((ext_vector_type(4))) float f32x4;
typedef __attribute__((ext_vector_type(16))) float f32x16;
typedef __attribute__((ext_vector_type(4))) u32 u32x4;

__device__ __forceinline__ u16 f2bf(float x) {
  __hip_bfloat16 h = __float2bfloat16(x);
  return __builtin_bit_cast(u16, h);
}

// packed f32->bf16 pair, RNE (single VALU op)
__device__ __forceinline__ u32 cvtpk(float lo, float hi) {
  u32 d;
  asm("v_cvt_pk_bf16_f32 %0, %1, %2" : "=v"(d) : "v"(lo), "v"(hi));
  return d;
}

#if __has_builtin(__builtin_amdgcn_exp2f)
#define EXP2(x) __builtin_amdgcn_exp2f(x)
#else
#define EXP2(x) __expf((x) * 0.6931471805599453f)
#endif

__device__ __forceinline__ bf16x8 mk_frag(u32 a, u32 b, u32 c, u32 d) {
  u32x4 v = {a, b, c, d};
  return __builtin_bit_cast(bf16x8, v);
}

__device__ __forceinline__ f32x16 mfma32(bf16x8 a, bf16x8 b, f32x16 c) {
  return __builtin_amdgcn_mfma_f32_32x32x16_bf16(a, b, c, 0, 0, 0);
}

__device__ __forceinline__ void gload16(const void* g, void* lds) {
  __builtin_amdgcn_global_load_lds((const __attribute__((address_space(1))) void*)g,
                                   (__attribute__((address_space(3))) void*)lds, 16, 0, 0);
}

// bijective XCD swizzle for nwg % 8 == 0: XCD x gets logical ids [x*cpx, (x+1)*cpx)
__device__ __forceinline__ int xcd_swz(int bid, int cpx) {
  return (bid & 7) * cpx + (bid >> 3);
}

// ---------------- fused: fp32->bf16 convert (q,kv) + all weight transposes ----------------
__global__ __launch_bounds__(256) void cvt_tw(const float* __restrict__ q, const float* __restrict__ kv,
                                              const float* __restrict__ Wq, const float* __restrict__ Wkv,
                                              const float* __restrict__ Wo, u16* __restrict__ qkbf,
                                              u16* __restrict__ wqt, u16* __restrict__ wkvt,
                                              u16* __restrict__ wot) {
  __shared__ float T[64][65];
  const int t = threadIdx.x;
  const int bid = blockIdx.x;
  if (bid < 4096) {
    int idx = bid * 256 + t;  // 8 elems each
    const float* src = (idx < 524288) ? q : kv;
    int li = idx & 524287;
    const float4* p = (const float4*)src + (size_t)li * 2;
    float4 a = p[0], b = p[1];
    bf16x8 vv;
    vv[0] = (short)f2bf(a.x); vv[1] = (short)f2bf(a.y);
    vv[2] = (short)f2bf(a.z); vv[3] = (short)f2bf(a.w);
    vv[4] = (short)f2bf(b.x); vv[5] = (short)f2bf(b.y);
    vv[6] = (short)f2bf(b.z); vv[7] = (short)f2bf(b.w);
    *(bf16x8*)(qkbf + (size_t)idx * 8) = vv;
    return;
  }
  const int wb = bid - 4096;
  const float* W; u16* Wt; int N, bx, by;
  if (wb < 256)      { W = Wq;  Wt = wqt;  N = 1024; bx = wb & 15; by = wb >> 4; }
  else if (wb < 512) { int b = wb - 256; W = Wo;  Wt = wot;  N = 1024; bx = b & 15; by = b >> 4; }
  else               { int b = wb - 512; W = Wkv; Wt = wkvt; N = 128;  bx = b & 1;  by = b >> 1; }
  const int K = 1024;
  const int n0 = bx * 64, k0 = by * 64;
  #pragma unroll
  for (int pass = 0; pass < 4; ++pass) {
    int r = pass * 16 + (t >> 4);
    int c = (t & 15) * 4;
    float4 v = *(const float4*)(W + (size_t)(k0 + r) * N + n0 + c);
    T[r][c] = v.x; T[r][c + 1] = v.y; T[r][c + 2] = v.z; T[r][c + 3] = v.w;
  }
  __syncthreads();
  #pragma unroll
  for (int s = 0; s < 2; ++s) {
    int n = s * 32 + (t >> 3);
    int kk = (t & 7) * 8;
    bf16x8 vv;
    #pragma unroll
    for (int i = 0; i < 8; ++i) vv[i] = (short)f2bf(T[kk + i][n]);
    *(bf16x8*)(Wt + (size_t)(n0 + n) * K + k0 + kk) = vv;
  }
}

// ---------------- output GEMM: C[M][N] = A[M][K] @ Bt[N][K]^T. BM=128,BN=64,BK=64 ----------------
// Double-buffered single-barrier pipeline (attn-proven): vmcnt(0)+barrier -> stage(next)
// -> compute(cur). Tile i+1's loads fly under compute(i). 48 KB LDS -> 3 blocks/CU.
// 1D grid 512, XCD-swizzled.
template<int BF16OUT>
__global__ __launch_bounds__(256, 3) void gemm_bt(const u16* __restrict__ A, const u16* __restrict__ Bt,
                                                  void* __restrict__ Cout, int N, int K, float scale) {
  __shared__ __attribute__((aligned(16))) u16 As[2][128 * 64];  // 16 KB each, rows 128B, swz ((row&7)<<4)
  __shared__ __attribute__((aligned(16))) u16 Bs[2][64 * 64];   // 8 KB each
  const int t = threadIdx.x;
  const int lane = t & 63, wv = t >> 6;
  const int g = lane >> 4, i16 = lane & 15;
  const int id = xcd_swz(blockIdx.x, 64);
  const int m0 = (id >> 4) * 128, n0 = (id & 15) * 64;
  const int wr = wv >> 1, wc = wv & 1;
  // it-invariant per-thread staging offsets (element units into A/Bt)
  int aO[4], bO[2];
  #pragma unroll
  for (int j = 0; j < 4; ++j) {
    int p = j * 4096 + t * 16;
    int row = p >> 7;
    int lg = (p & 127) ^ ((row & 7) << 4);
    aO[j] = (m0 + row) * K + (lg >> 1);
  }
  #pragma unroll
  for (int j = 0; j < 2; ++j) {
    int p = j * 4096 + t * 16;
    int row = p >> 7;
    int lg = (p & 127) ^ ((row & 7) << 4);
    bO[j] = (n0 + row) * K + (lg >> 1);
  }
  auto stage = [&](int b, int kt) {
    #pragma unroll
    for (int j = 0; j < 4; ++j)
      gload16(A + (size_t)(aO[j] + kt), (char*)As[b] + j * 4096 + t * 16);
    #pragma unroll
    for (int j = 0; j < 2; ++j)
      gload16(Bt + (size_t)(bO[j] + kt), (char*)Bs[b] + j * 4096 + t * 16);
  };
  f32x4 acc[4][2] = {};
  const int NT = K >> 6;  // 16
  stage(0, 0);
  for (int it = 0; it < NT; ++it) {
    asm volatile("s_waitcnt vmcnt(0)" ::: "memory");
    __builtin_amdgcn_s_barrier();
    if (it + 1 < NT) stage((it + 1) & 1, (it + 1) << 6);
    const char* Ab = (const char*)As[it & 1];
    const char* Bb = (const char*)Bs[it & 1];
    bf16x8 af[2][4], bfr[2][2];
    #pragma unroll
    for (int kf = 0; kf < 2; ++kf) {
      #pragma unroll
      for (int x = 0; x < 4; ++x) {
        int ra = wr * 64 + x * 16 + i16;
        af[kf][x] = *(const bf16x8*)(Ab + ((ra * 128 + kf * 64 + g * 16) ^ ((ra & 7) << 4)));
      }
      #pragma unroll
      for (int x = 0; x < 2; ++x) {
        int rb = wc * 32 + x * 16 + i16;
        bfr[kf][x] = *(const bf16x8*)(Bb + ((rb * 128 + kf * 64 + g * 16) ^ ((rb & 7) << 4)));
      }
    }
    #pragma unroll
    for (int kf = 0; kf < 2; ++kf)
      #pragma unroll
      for (int mi = 0; mi < 4; ++mi)
        #pragma unroll
        for (int ni = 0; ni < 2; ++ni)
          acc[mi][ni] = __builtin_amdgcn_mfma_f32_16x16x32_bf16(af[kf][mi], bfr[kf][ni], acc[mi][ni], 0, 0, 0);
  }
  #pragma unroll
  for (int mi = 0; mi < 4; ++mi)
    #pragma unroll
    for (int ni = 0; ni < 2; ++ni)
      #pragma unroll
      for (int r = 0; r < 4; ++r) {
        size_t off = (size_t)(m0 + wr * 64 + mi * 16 + g * 4 + r) * N + (n0 + wc * 32 + ni * 16 + i16);
        float v = acc[mi][ni][r] * scale;
        if (BF16OUT) ((u16*)Cout)[off] = f2bf(v);
        else ((float*)Cout)[off] = v;
      }
}

// ---------------- fused q/kv projection GEMM (576 blocks), BK=64, pipelined, swizzled ----------------
__global__ __launch_bounds__(256, 3) void gemm_qkv(const u16* __restrict__ qbf, const u16* __restrict__ kvbf,
                                                   const u16* __restrict__ wqt, const u16* __restrict__ wkvt,
                                                   u16* __restrict__ qp, u16* __restrict__ kvp,
                                                   u16* __restrict__ vtg) {
  __shared__ __attribute__((aligned(16))) u16 As[2][128 * 64];
  __shared__ __attribute__((aligned(16))) u16 Bs[2][64 * 64];
  const int t = threadIdx.x;
  const int lane = t & 63, wv = t >> 6;
  const int g = lane >> 4, i16 = lane & 15;
  const int wr = wv >> 1, wc = wv & 1;
  const int K = 1024;
  const int id = xcd_swz(blockIdx.x, 72);
  const bool iskv = id >= 512;
  const u16* A; const u16* Bt; int m0, n0;
  if (!iskv) { A = qbf;  Bt = wqt;  m0 = (id >> 4) * 128; n0 = (id & 15) * 64; }
  else       { int b = id - 512; A = kvbf; Bt = wkvt; m0 = (b >> 1) * 128; n0 = (b & 1) * 64; }
  int aO[4], bO[2];
  #pragma unroll
  for (int j = 0; j < 4; ++j) {
    int p = j * 4096 + t * 16;
    int row = p >> 7;
    int lg = (p & 127) ^ ((row & 7) << 4);
    aO[j] = (m0 + row) * K + (lg >> 1);
  }
  #pragma unroll
  for (int j = 0; j < 2; ++j) {
    int p = j * 4096 + t * 16;
    int row = p >> 7;
    int lg = (p & 127) ^ ((row & 7) << 4);
    bO[j] = (n0 + row) * K + (lg >> 1);
  }
  auto stage = [&](int b, int kt) {
    #pragma unroll
    for (int j = 0; j < 4; ++j)
      gload16(A + (size_t)(aO[j] + kt), (char*)As[b] + j * 4096 + t * 16);
    #pragma unroll
    for (int j = 0; j < 2; ++j)
      gload16(Bt + (size_t)(bO[j] + kt), (char*)Bs[b] + j * 4096 + t * 16);
  };
  f32x4 acc[4][2] = {};
  const int NT = 16;
  stage(0, 0);
  for (int it = 0; it < NT; ++it) {
    asm volatile("s_waitcnt vmcnt(0)" ::: "memory");
    __builtin_amdgcn_s_barrier();
    if (it + 1 < NT) stage((it + 1) & 1, (it + 1) << 6);
    const char* Ab = (const char*)As[it & 1];
    const char* Bb = (const char*)Bs[it & 1];
    bf16x8 af[2][4], bfr[2][2];
    #pragma unroll
    for (int kf = 0; kf < 2; ++kf) {
      #pragma unroll
      for (int x = 0; x < 4; ++x) {
        int ra = wr * 64 + x * 16 + i16;
        af[kf][x] = *(const bf16x8*)(Ab + ((ra * 128 + kf * 64 + g * 16) ^ ((ra & 7) << 4)));
      }
      #pragma unroll
      for (int x = 0; x < 2; ++x) {
        int rb = wc * 32 + x * 16 + i16;
        bfr[kf][x] = *(const bf16x8*)(Bb + ((rb * 128 + kf * 64 + g * 16) ^ ((rb & 7) << 4)));
      }
    }
    #pragma unroll
    for (int kf = 0; kf < 2; ++kf)
      #pragma unroll
      for (int mi = 0; mi < 4; ++mi)
        #pragma unroll
        for (int ni = 0; ni < 2; ++ni)
          acc[mi][ni] = __builtin_amdgcn_mfma_f32_16x16x32_bf16(af[kf][mi], bfr[kf][ni], acc[mi][ni], 0, 0, 0);
  }
  if (!iskv) {
    // scale folds 1/sqrt(64) * log2(e): attention softmax runs in exp2 domain
    #pragma unroll
    for (int mi = 0; mi < 4; ++mi)
      #pragma unroll
      for (int ni = 0; ni < 2; ++ni)
        #pragma unroll
        for (int r = 0; r < 4; ++r)
          qp[(size_t)(m0 + wr * 64 + mi * 16 + g * 4 + r) * 1024 + n0 + wc * 32 + ni * 16 + i16] =
              f2bf(acc[mi][ni][r] * 0.18033688011112042f);
  } else if (n0 == 0) {
    // K-half: kvp[key][0..63], stride 64
    #pragma unroll
    for (int mi = 0; mi < 4; ++mi)
      #pragma unroll
      for (int ni = 0; ni < 2; ++ni)
        #pragma unroll
        for (int r = 0; r < 4; ++r)
          kvp[(size_t)(m0 + wr * 64 + mi * 16 + g * 4 + r) * 64 + wc * 32 + ni * 16 + i16] =
              f2bf(acc[mi][ni][r]);
  } else {
    // V-half: write transposed via LDS re-tile -> vtg[d][key]
    __syncthreads();  // all waves done with As before reuse as CT
    u16* CT = (u16*)&As[0][0];  // 64 x 128
    #pragma unroll
    for (int mi = 0; mi < 4; ++mi)
      #pragma unroll
      for (int ni = 0; ni < 2; ++ni)
        #pragma unroll
        for (int r = 0; r < 4; ++r)
          CT[(wc * 32 + ni * 16 + i16) * 128 + wr * 64 + mi * 16 + g * 4 + r] = f2bf(acc[mi][ni][r]);
    __syncthreads();
    int d = t >> 2, c4 = t & 3;
    const u16* src = CT + d * 128 + c4 * 32;
    u16* dst = vtg + (size_t)d * 4096 + m0 + c4 * 32;
    #pragma unroll
    for (int j = 0; j < 4; ++j)
      *(bf16x8*)(dst + j * 8) = *(const bf16x8*)(src + j * 8);
  }
}

// ---------------- windowed flash attention: 4-wave blocks, 64 q/wave (2 sets), split-K ----------
// R13 structure verbatim (best measured: 82.0 us total; R15's setprio was -2.5 us -> reverted).
__global__ __launch_bounds__(256, 2) void attn_kernel(const u16* __restrict__ qp, const u16* __restrict__ kvp,
                                                      const u16* __restrict__ vtg, u16* __restrict__ ctx) {
  __shared__ __attribute__((aligned(16))) u16 Ks[2][2][64 * 64];  // [group][buf][key][d], swz ((key&7)<<4)
  __shared__ __attribute__((aligned(16))) u16 Vs[2][2][64 * 64];  // [group][buf][d][key], swz ((d&7)<<4)
  const int t = threadIdx.x;
  const int lane = t & 63, wv = t >> 6;
  const int g2 = wv >> 1, wq = wv & 1;
  const int tg = t & 127;
  const int hh = lane >> 5, q32 = lane & 31;
  const int id = xcd_swz(blockIdx.x, 64);
  const int qt = id & 3, hd = (id >> 2) & 15, c = id >> 6;
  const int q0 = c * 512 + qt * 128 + wq * 64;
  const int pk32 = (q32 & 19) | ((q32 & 4) << 1) | ((q32 & 8) >> 1);  // swap bits 2<->3

  bf16x8 qfA[4], qfB[4];
  #pragma unroll
  for (int dt = 0; dt < 4; ++dt) {
    qfA[dt] = *(const bf16x8*)(qp + (size_t)(q0 + q32) * 1024 + hd * 64 + dt * 16 + hh * 8);
    qfB[dt] = *(const bf16x8*)(qp + (size_t)(q0 + 32 + q32) * 1024 + hd * 64 + dt * 16 + hh * 8);
  }

  const int kb0 = (c - 1) * 512;
  const int v0 = (c == 0) ? 8 : 0;
  const int nv = (c == 0 || c == 7) ? 16 : 24;   // valid tiles (contiguous, always even)
  const int n2 = nv >> 1;
  const int s0 = v0 + g2 * n2;                   // this group's first tile
  const float lpad = g2 ? 0.f : 32.f * (float)(24 - nv);
  float lA = lpad, lB = lpad;                    // zero-pad keys: exp2(0)=1 each
  f32x16 accA[2] = {}, accB[2] = {};

  // it-invariant per-thread staging offsets (element units); 128 threads/group, 4 rounds
  int kA[4], vA[4];
  #pragma unroll
  for (int j = 0; j < 4; ++j) {
    int p = j * 2048 + tg * 16;
    int row = p >> 7;
    int lg = (p & 127) ^ ((row & 7) << 4);
    kA[j] = row * 64 + (lg >> 1);
    vA[j] = row * 4096 + (lg >> 1);
  }

  auto stage = [&](int b, int tile) {
    const int kb = kb0 + tile * 64;
    #pragma unroll
    for (int j = 0; j < 4; ++j)
      gload16(kvp + (size_t)(kb * 64 + kA[j]), (char*)Ks[g2][b] + j * 2048 + tg * 16);
    #pragma unroll
    for (int j = 0; j < 4; ++j)
      gload16(vtg + (size_t)(kb + vA[j]), (char*)Vs[g2][b] + j * 2048 + tg * 16);
  };

  stage(0, s0);

  for (int i = 0; i < n2; ++i) {
    asm volatile("s_waitcnt vmcnt(0)" ::: "memory");  // tile-i loads landed (flew during compute(i-1))
    __builtin_amdgcn_s_barrier();
    if (i + 1 < n2) stage((i + 1) & 1, s0 + i + 1);
    const char* kbase0 = (const char*)Ks[g2][i & 1];
    const char* vbase0 = (const char*)Vs[g2][i & 1];
    // ---- QK^T both sets (K fragments shared): lane = one q, regs = keys ----
    f32x16 sA[2] = {}, sB[2] = {};
    #pragma unroll
    for (int kt = 0; kt < 2; ++kt) {
      const char* kbase = kbase0 + kt * 4096 + pk32 * 128;
      int kswz = (pk32 & 7) << 4;
      #pragma unroll
      for (int dt = 0; dt < 4; ++dt) {
        bf16x8 kf = *(const bf16x8*)(kbase + ((dt * 32 + hh * 16) ^ kswz));
        sA[kt] = mfma32(kf, qfA[dt], sA[kt]);
        sB[kt] = mfma32(kf, qfB[dt], sB[kt]);
      }
    }
    // ---- no-max exp2 softmax both sets; PV shares V fragments ----
    #pragma unroll
    for (int kt = 0; kt < 2; ++kt) {
      #pragma unroll
      for (int r = 0; r < 16; ++r) sA[kt][r] = EXP2(sA[kt][r]);
      #pragma unroll
      for (int r = 0; r < 16; ++r) sB[kt][r] = EXP2(sB[kt][r]);
      lA += (((sA[kt][0] + sA[kt][1]) + (sA[kt][2] + sA[kt][3])) + ((sA[kt][4] + sA[kt][5]) + (sA[kt][6] + sA[kt][7]))) +
            (((sA[kt][8] + sA[kt][9]) + (sA[kt][10] + sA[kt][11])) + ((sA[kt][12] + sA[kt][13]) + (sA[kt][14] + sA[kt][15])));
      lB += (((sB[kt][0] + sB[kt][1]) + (sB[kt][2] + sB[kt][3])) + ((sB[kt][4] + sB[kt][5]) + (sB[kt][6] + sB[kt][7]))) +
            (((sB[kt][8] + sB[kt][9]) + (sB[kt][10] + sB[kt][11])) + ((sB[kt][12] + sB[kt][13]) + (sB[kt][14] + sB[kt][15])));
      u32 wA[8], wB[8];
      #pragma unroll
      for (int j = 0; j < 8; ++j) wA[j] = cvtpk(sA[kt][2 * j], sA[kt][2 * j + 1]);
      #pragma unroll
      for (int j = 0; j < 8; ++j) wB[j] = cvtpk(sB[kt][2 * j], sB[kt][2 * j + 1]);
      bf16x8 pbA0 = mk_frag(wA[0], wA[1], wA[2], wA[3]);
      bf16x8 pbA1 = mk_frag(wA[4], wA[5], wA[6], wA[7]);
      bf16x8 pbB0 = mk_frag(wB[0], wB[1], wB[2], wB[3]);
      bf16x8 pbB1 = mk_frag(wB[4], wB[5], wB[6], wB[7]);
      int vswz = (q32 & 7) << 4;
      #pragma unroll
      for (int dtv = 0; dtv < 2; ++dtv) {
        const char* vbase = vbase0 + dtv * 4096 + q32 * 128;
        bf16x8 va0 = *(const bf16x8*)(vbase + ((kt * 64 + hh * 16) ^ vswz));
        accA[dtv] = mfma32(va0, pbA0, accA[dtv]);
        accB[dtv] = mfma32(va0, pbB0, accB[dtv]);
        bf16x8 va1 = *(const bf16x8*)(vbase + ((kt * 64 + 32 + hh * 16) ^ vswz));
        accA[dtv] = mfma32(va1, pbA1, accA[dtv]);
        accB[dtv] = mfma32(va1, pbB1, accB[dtv]);
      }
    }
  }

  // ---- merge: group 1 hands (acc, l) to group 0 via LDS ----
  __syncthreads();
  char* M = (char*)&Ks[0][0][0];                    // 32 KB: acc exchange, [wq][set] regions
  float* Lx = (float*)((char*)&Vs[0][0][0] + 24576);// 1 KB: l exchange
  if (g2 == 1) {
    #pragma unroll
    for (int set = 0; set < 2; ++set) {
      const f32x16* ac = set ? accB : accA;
      #pragma unroll
      for (int dtv = 0; dtv < 2; ++dtv)
        #pragma unroll
        for (int j = 0; j < 4; ++j) {
          f32x4 chunk = {ac[dtv][4 * j], ac[dtv][4 * j + 1], ac[dtv][4 * j + 2], ac[dtv][4 * j + 3]};
          int byte = lane * 128 + dtv * 64 + j * 16;
          *(f32x4*)(M + wq * 16384 + set * 8192 + (byte ^ ((lane & 7) << 4))) = chunk;
        }
      Lx[(wq * 2 + set) * 64 + lane] = set ? lB : lA;
    }
  }
  __syncthreads();
  if (g2 == 0) {
    #pragma unroll
    for (int set = 0; set < 2; ++set) {
      f32x16* ac = set ? accB : accA;
      #pragma unroll
      for (int dtv = 0; dtv < 2; ++dtv)
        #pragma unroll
        for (int j = 0; j < 4; ++j) {
          int byte = lane * 128 + dtv * 64 + j * 16;
          f32x4 chunk = *(const f32x4*)(M + wq * 16384 + set * 8192 + (byte ^ ((lane & 7) << 4)));
          #pragma unroll
          for (int e = 0; e < 4; ++e) ac[dtv][4 * j + e] += chunk[e];
        }
      float l = (set ? lB : lA) + Lx[(wq * 2 + set) * 64 + lane];
      l += __shfl_xor(l, 32);
      float rl = 1.0f / l;
      // epilogue: O^T -> per-wave 4 KB LDS region -> row-major vector store
      char* Ow = (char*)&Vs[0][0][0] + wq * 4096;
      #pragma unroll
      for (int dtv = 0; dtv < 2; ++dtv)
        #pragma unroll
        for (int j = 0; j < 4; ++j) {
          int d = dtv * 32 + 8 * j + 4 * hh;
          uint2 wp;
          wp.x = cvtpk(ac[dtv][4 * j] * rl, ac[dtv][4 * j + 1] * rl);
          wp.y = cvtpk(ac[dtv][4 * j + 2] * rl, ac[dtv][4 * j + 3] * rl);
          *(uint2*)(Ow + q32 * 128 + ((d * 2) ^ ((q32 & 7) << 4))) = wp;
        }
      asm volatile("s_waitcnt lgkmcnt(0)" ::: "memory");
      __builtin_amdgcn_sched_barrier(0);
      #pragma unroll
      for (int rep = 0; rep < 4; ++rep) {
        int q = lane >> 1, dblk = (lane & 1) * 4 + rep, d0 = dblk * 8;
        bf16x8 ov = *(const bf16x8*)(Ow + q * 128 + ((d0 * 2) ^ ((q & 7) << 4)));
        *(bf16x8*)(ctx + (size_t)(q0 + set * 32 + q) * 1024 + hd * 64 + d0) = ov;
      }
      asm volatile("s_waitcnt lgkmcnt(0) vmcnt(0)" ::: "memory");  // region reuse between sets
      __builtin_amdgcn_sched_barrier(0);
    }
  }
}

extern "C" void kernel_launch(void* const* d_in, const int* in_sizes, int n_in,
                              void* d_out, int out_size, void* d_ws, size_t ws_size,
                              hipStream_t stream) {
  const float* q   = (const float*)d_in[0];
  const float* kv  = (const float*)d_in[1];
  const float* Wq  = (const float*)d_in[2];
  const float* Wkv = (const float*)d_in[3];
  const float* Wo  = (const float*)d_in[4];
  char* ws = (char*)d_ws;
  u16* qbf  = (u16*)(ws);                // 8 MB   cvt_tw -> gemm_qkv
  u16* ctx  = (u16*)(ws);                // 8 MB   attn -> gemm_out (over dead qbf)
  u16* kvbf = (u16*)(ws + 8388608);      // 8 MB   cvt_tw -> gemm_qkv
  u16* qp   = (u16*)(ws + 16777216);     // 8 MB   gemm_qkv -> attn
  u16* kvp  = (u16*)(ws + 25165824);     // 512 KB gemm_qkv -> attn (K, [4096][64])
  u16* vtg  = (u16*)(ws + 25690112);     // 512 KB gemm_qkv -> attn (V^T, [64][4096])
  u16* wqt  = (u16*)(ws + 26214400);     // 2 MB
  u16* wkvt = (u16*)(ws + 28311552);     // 256 KB
  u16* wot  = (u16*)(ws + 28573696);     // 2 MB
  cvt_tw<<<4640, 256, 0, stream>>>(q, kv, Wq, Wkv, Wo, qbf, wqt, wkvt, wot);
  gemm_qkv<<<576, 256, 0, stream>>>(qbf, kvbf, wqt, wkvt, qp, kvp, vtg);
  attn_kernel<<<512, 256, 0, stream>>>(qp, kvp, vtg, ctx);
  gemm_bt<0><<<512, 256, 0, stream>>>(ctx, wot, (float*)d_out, 1024, 1024, 1.0f);
}

// Round 17
// 81.938 us; speedup vs baseline: 1.0369x; 1.0369x over previous
//
#include <hip/hip_runtime.h>
#include <hip/hip_bf16.h>

typedef unsigned short u16;
typedef unsigned int u32;
typedef __attribute__((ext_vector_type(8))) short bf16x8;
typedef __attribute__((ext_vector_type(4))) float f32x4;
typedef __attribute__((ext_vector_type(16))) float f32x16;
typedef __attribute__((ext_vector_type(4))) u32 u32x4;

__device__ __forceinline__ u16 f2bf(float x) {
  __hip_bfloat16 h = __float2bfloat16(x);
  return __builtin_bit_cast(u16, h);
}

// packed f32->bf16 pair, RNE (single VALU op)
__device__ __forceinline__ u32 cvtpk(float lo, float hi) {
  u32 d;
  asm("v_cvt_pk_bf16_f32 %0, %1, %2" : "=v"(d) : "v"(lo), "v"(hi));
  return d;
}

#if __has_builtin(__builtin_amdgcn_exp2f)
#define EXP2(x) __builtin_amdgcn_exp2f(x)
#else
#define EXP2(x) __expf((x) * 0.6931471805599453f)
#endif

__device__ __forceinline__ bf16x8 mk_frag(u32 a, u32 b, u32 c, u32 d) {
  u32x4 v = {a, b, c, d};
  return __builtin_bit_cast(bf16x8, v);
}

__device__ __forceinline__ f32x16 mfma32(bf16x8 a, bf16x8 b, f32x16 c) {
  return __builtin_amdgcn_mfma_f32_32x32x16_bf16(a, b, c, 0, 0, 0);
}

__device__ __forceinline__ void gload16(const void* g, void* lds) {
  __builtin_amdgcn_global_load_lds((const __attribute__((address_space(1))) void*)g,
                                   (__attribute__((address_space(3))) void*)lds, 16, 0, 0);
}

// bijective XCD swizzle for nwg % 8 == 0: XCD x gets logical ids [x*cpx, (x+1)*cpx)
__device__ __forceinline__ int xcd_swz(int bid, int cpx) {
  return (bid & 7) * cpx + (bid >> 3);
}

// ---------------- fused: fp32->bf16 convert (q,kv) + all weight transposes ----------------
__global__ __launch_bounds__(256) void cvt_tw(const float* __restrict__ q, const float* __restrict__ kv,
                                              const float* __restrict__ Wq, const float* __restrict__ Wkv,
                                              const float* __restrict__ Wo, u16* __restrict__ qkbf,
                                              u16* __restrict__ wqt, u16* __restrict__ wkvt,
                                              u16* __restrict__ wot) {
  __shared__ float T[64][65];
  const int t = threadIdx.x;
  const int bid = blockIdx.x;
  if (bid < 4096) {
    int idx = bid * 256 + t;  // 8 elems each
    const float* src = (idx < 524288) ? q : kv;
    int li = idx & 524287;
    const float4* p = (const float4*)src + (size_t)li * 2;
    float4 a = p[0], b = p[1];
    bf16x8 vv;
    vv[0] = (short)f2bf(a.x); vv[1] = (short)f2bf(a.y);
    vv[2] = (short)f2bf(a.z); vv[3] = (short)f2bf(a.w);
    vv[4] = (short)f2bf(b.x); vv[5] = (short)f2bf(b.y);
    vv[6] = (short)f2bf(b.z); vv[7] = (short)f2bf(b.w);
    *(bf16x8*)(qkbf + (size_t)idx * 8) = vv;
    return;
  }
  const int wb = bid - 4096;
  const float* W; u16* Wt; int N, bx, by;
  if (wb < 256)      { W = Wq;  Wt = wqt;  N = 1024; bx = wb & 15; by = wb >> 4; }
  else if (wb < 512) { int b = wb - 256; W = Wo;  Wt = wot;  N = 1024; bx = b & 15; by = b >> 4; }
  else               { int b = wb - 512; W = Wkv; Wt = wkvt; N = 128;  bx = b & 1;  by = b >> 1; }
  const int K = 1024;
  const int n0 = bx * 64, k0 = by * 64;
  #pragma unroll
  for (int pass = 0; pass < 4; ++pass) {
    int r = pass * 16 + (t >> 4);
    int c = (t & 15) * 4;
    float4 v = *(const float4*)(W + (size_t)(k0 + r) * N + n0 + c);
    T[r][c] = v.x; T[r][c + 1] = v.y; T[r][c + 2] = v.z; T[r][c + 3] = v.w;
  }
  __syncthreads();
  #pragma unroll
  for (int s = 0; s < 2; ++s) {
    int n = s * 32 + (t >> 3);
    int kk = (t & 7) * 8;
    bf16x8 vv;
    #pragma unroll
    for (int i = 0; i < 8; ++i) vv[i] = (short)f2bf(T[kk + i][n]);
    *(bf16x8*)(Wt + (size_t)(n0 + n) * K + k0 + kk) = vv;
  }
}

// ---------------- output GEMM: C[M][N] = A[M][K] @ Bt[N][K]^T. BM=128,BN=64,BK=128 ----------------
// 1D grid 512, XCD-swizzled: each XCD owns 4 consecutive m-rows (A-panels L2-local).
template<int BF16OUT>
__global__ __launch_bounds__(256, 3) void gemm_bt(const u16* __restrict__ A, const u16* __restrict__ Bt,
                                                  void* __restrict__ Cout, int N, int K, float scale) {
  __shared__ __attribute__((aligned(16))) u16 As[128 * 128];  // 32 KB, rows 256B, swz ((row&15)<<4)
  __shared__ __attribute__((aligned(16))) u16 Bs[64 * 128];   // 16 KB
  const int t = threadIdx.x;
  const int lane = t & 63, wv = t >> 6;
  const int g = lane >> 4, i16 = lane & 15;
  const int id = xcd_swz(blockIdx.x, 64);
  const int m0 = (id >> 4) * 128, n0 = (id & 15) * 64;
  const int wr = wv >> 1, wc = wv & 1;
  f32x4 acc[4][2] = {};
  for (int kt = 0; kt < K; kt += 128) {
    #pragma unroll
    for (int j = 0; j < 8; ++j) {
      int p = j * 4096 + t * 16;
      int row = p >> 8;
      int lg = (p & 255) ^ ((row & 15) << 4);
      gload16(A + (size_t)(m0 + row) * K + kt + (lg >> 1), (char*)As + p);
    }
    #pragma unroll
    for (int j = 0; j < 4; ++j) {
      int p = j * 4096 + t * 16;
      int row = p >> 8;
      int lg = (p & 255) ^ ((row & 15) << 4);
      gload16(Bt + (size_t)(n0 + row) * K + kt + (lg >> 1), (char*)Bs + p);
    }
    __syncthreads();
    bf16x8 af[4][4], bfr[4][2];
    #pragma unroll
    for (int kf = 0; kf < 4; ++kf) {
      #pragma unroll
      for (int x = 0; x < 4; ++x) {
        int ra = wr * 64 + x * 16 + i16;
        af[kf][x] = *(const bf16x8*)((const char*)As + ((ra * 256 + kf * 64 + g * 16) ^ ((ra & 15) << 4)));
      }
      #pragma unroll
      for (int x = 0; x < 2; ++x) {
        int rb = wc * 32 + x * 16 + i16;
        bfr[kf][x] = *(const bf16x8*)((const char*)Bs + ((rb * 256 + kf * 64 + g * 16) ^ ((rb & 15) << 4)));
      }
    }
    #pragma unroll
    for (int kf = 0; kf < 4; ++kf)
      #pragma unroll
      for (int mi = 0; mi < 4; ++mi)
        #pragma unroll
        for (int ni = 0; ni < 2; ++ni)
          acc[mi][ni] = __builtin_amdgcn_mfma_f32_16x16x32_bf16(af[kf][mi], bfr[kf][ni], acc[mi][ni], 0, 0, 0);
    __syncthreads();
  }
  #pragma unroll
  for (int mi = 0; mi < 4; ++mi)
    #pragma unroll
    for (int ni = 0; ni < 2; ++ni)
      #pragma unroll
      for (int r = 0; r < 4; ++r) {
        size_t off = (size_t)(m0 + wr * 64 + mi * 16 + g * 4 + r) * N + (n0 + wc * 32 + ni * 16 + i16);
        float v = acc[mi][ni][r] * scale;
        if (BF16OUT) ((u16*)Cout)[off] = f2bf(v);
        else ((float*)Cout)[off] = v;
      }
}

// ---------------- fused q-projection + kv-projection GEMM (576 blocks), BK=128, swizzled ----------------
__global__ __launch_bounds__(256, 3) void gemm_qkv(const u16* __restrict__ qbf, const u16* __restrict__ kvbf,
                                                   const u16* __restrict__ wqt, const u16* __restrict__ wkvt,
                                                   u16* __restrict__ qp, u16* __restrict__ kvp,
                                                   u16* __restrict__ vtg) {
  __shared__ __attribute__((aligned(16))) u16 As[128 * 128];
  __shared__ __attribute__((aligned(16))) u16 Bs[64 * 128];
  const int t = threadIdx.x;
  const int lane = t & 63, wv = t >> 6;
  const int g = lane >> 4, i16 = lane & 15;
  const int wr = wv >> 1, wc = wv & 1;
  const int K = 1024;
  const int id = xcd_swz(blockIdx.x, 72);
  const bool iskv = id >= 512;
  const u16* A; const u16* Bt; int m0, n0;
  if (!iskv) { A = qbf;  Bt = wqt;  m0 = (id >> 4) * 128; n0 = (id & 15) * 64; }
  else       { int b = id - 512; A = kvbf; Bt = wkvt; m0 = (b >> 1) * 128; n0 = (b & 1) * 64; }
  f32x4 acc[4][2] = {};
  for (int kt = 0; kt < K; kt += 128) {
    #pragma unroll
    for (int j = 0; j < 8; ++j) {
      int p = j * 4096 + t * 16;
      int row = p >> 8;
      int lg = (p & 255) ^ ((row & 15) << 4);
      gload16(A + (size_t)(m0 + row) * K + kt + (lg >> 1), (char*)As + p);
    }
    #pragma unroll
    for (int j = 0; j < 4; ++j) {
      int p = j * 4096 + t * 16;
      int row = p >> 8;
      int lg = (p & 255) ^ ((row & 15) << 4);
      gload16(Bt + (size_t)(n0 + row) * K + kt + (lg >> 1), (char*)Bs + p);
    }
    __syncthreads();
    bf16x8 af[4][4], bfr[4][2];
    #pragma unroll
    for (int kf = 0; kf < 4; ++kf) {
      #pragma unroll
      for (int x = 0; x < 4; ++x) {
        int ra = wr * 64 + x * 16 + i16;
        af[kf][x] = *(const bf16x8*)((const char*)As + ((ra * 256 + kf * 64 + g * 16) ^ ((ra & 15) << 4)));
      }
      #pragma unroll
      for (int x = 0; x < 2; ++x) {
        int rb = wc * 32 + x * 16 + i16;
        bfr[kf][x] = *(const bf16x8*)((const char*)Bs + ((rb * 256 + kf * 64 + g * 16) ^ ((rb & 15) << 4)));
      }
    }
    #pragma unroll
    for (int kf = 0; kf < 4; ++kf)
      #pragma unroll
      for (int mi = 0; mi < 4; ++mi)
        #pragma unroll
        for (int ni = 0; ni < 2; ++ni)
          acc[mi][ni] = __builtin_amdgcn_mfma_f32_16x16x32_bf16(af[kf][mi], bfr[kf][ni], acc[mi][ni], 0, 0, 0);
    __syncthreads();
  }
  if (!iskv) {
    // scale folds 1/sqrt(64) * log2(e): attention softmax runs in exp2 domain
    #pragma unroll
    for (int mi = 0; mi < 4; ++mi)
      #pragma unroll
      for (int ni = 0; ni < 2; ++ni)
        #pragma unroll
        for (int r = 0; r < 4; ++r)
          qp[(size_t)(m0 + wr * 64 + mi * 16 + g * 4 + r) * 1024 + n0 + wc * 32 + ni * 16 + i16] =
              f2bf(acc[mi][ni][r] * 0.18033688011112042f);
  } else if (n0 == 0) {
    // K-half: kvp[key][0..63], stride 64
    #pragma unroll
    for (int mi = 0; mi < 4; ++mi)
      #pragma unroll
      for (int ni = 0; ni < 2; ++ni)
        #pragma unroll
        for (int r = 0; r < 4; ++r)
          kvp[(size_t)(m0 + wr * 64 + mi * 16 + g * 4 + r) * 64 + wc * 32 + ni * 16 + i16] =
              f2bf(acc[mi][ni][r]);
  } else {
    // V-half: write transposed via LDS re-tile -> vtg[d][key]
    u16* CT = (u16*)As;  // 64 x 128
    #pragma unroll
    for (int mi = 0; mi < 4; ++mi)
      #pragma unroll
      for (int ni = 0; ni < 2; ++ni)
        #pragma unroll
        for (int r = 0; r < 4; ++r)
          CT[(wc * 32 + ni * 16 + i16) * 128 + wr * 64 + mi * 16 + g * 4 + r] = f2bf(acc[mi][ni][r]);
    __syncthreads();
    int d = t >> 2, c4 = t & 3;
    const u16* src = CT + d * 128 + c4 * 32;
    u16* dst = vtg + (size_t)d * 4096 + m0 + c4 * 32;
    #pragma unroll
    for (int j = 0; j < 4; ++j)
      *(bf16x8*)(dst + j * 8) = *(const bf16x8*)(src + j * 8);
  }
}

// ---------------- windowed flash attention: 4-wave blocks, 64 q/wave (2 sets), split-K ----------
// R13 structure verbatim (best measured: 82.0 us total). XCD swizzle: all 64 blocks of one
// chunk c on one XCD -> K/V slice L2-local. No-max exp2 softmax; permuted-key load keeps
// S^T regs in PV B-layout (zero shuffles); split-K merge via LDS.
__global__ __launch_bounds__(256, 2) void attn_kernel(const u16* __restrict__ qp, const u16* __restrict__ kvp,
                                                      const u16* __restrict__ vtg, u16* __restrict__ ctx) {
  __shared__ __attribute__((aligned(16))) u16 Ks[2][2][64 * 64];  // [group][buf][key][d], swz ((key&7)<<4)
  __shared__ __attribute__((aligned(16))) u16 Vs[2][2][64 * 64];  // [group][buf][d][key], swz ((d&7)<<4)
  const int t = threadIdx.x;
  const int lane = t & 63, wv = t >> 6;
  const int g2 = wv >> 1, wq = wv & 1;
  const int tg = t & 127;
  const int hh = lane >> 5, q32 = lane & 31;
  const int id = xcd_swz(blockIdx.x, 64);
  const int qt = id & 3, hd = (id >> 2) & 15, c = id >> 6;
  const int q0 = c * 512 + qt * 128 + wq * 64;
  const int pk32 = (q32 & 19) | ((q32 & 4) << 1) | ((q32 & 8) >> 1);  // swap bits 2<->3

  bf16x8 qfA[4], qfB[4];
  #pragma unroll
  for (int dt = 0; dt < 4; ++dt) {
    qfA[dt] = *(const bf16x8*)(qp + (size_t)(q0 + q32) * 1024 + hd * 64 + dt * 16 + hh * 8);
    qfB[dt] = *(const bf16x8*)(qp + (size_t)(q0 + 32 + q32) * 1024 + hd * 64 + dt * 16 + hh * 8);
  }

  const int kb0 = (c - 1) * 512;
  const int v0 = (c == 0) ? 8 : 0;
  const int nv = (c == 0 || c == 7) ? 16 : 24;   // valid tiles (contiguous, always even)
  const int n2 = nv >> 1;
  const int s0 = v0 + g2 * n2;                   // this group's first tile
  const float lpad = g2 ? 0.f : 32.f * (float)(24 - nv);
  float lA = lpad, lB = lpad;                    // zero-pad keys: exp2(0)=1 each
  f32x16 accA[2] = {}, accB[2] = {};

  // it-invariant per-thread staging offsets (element units); 128 threads/group, 4 rounds
  int kA[4], vA[4];
  #pragma unroll
  for (int j = 0; j < 4; ++j) {
    int p = j * 2048 + tg * 16;
    int row = p >> 7;
    int lg = (p & 127) ^ ((row & 7) << 4);
    kA[j] = row * 64 + (lg >> 1);
    vA[j] = row * 4096 + (lg >> 1);
  }

  auto stage = [&](int b, int tile) {
    const int kb = kb0 + tile * 64;
    #pragma unroll
    for (int j = 0; j < 4; ++j)
      gload16(kvp + (size_t)(kb * 64 + kA[j]), (char*)Ks[g2][b] + j * 2048 + tg * 16);
    #pragma unroll
    for (int j = 0; j < 4; ++j)
      gload16(vtg + (size_t)(kb + vA[j]), (char*)Vs[g2][b] + j * 2048 + tg * 16);
  };

  stage(0, s0);

  for (int i = 0; i < n2; ++i) {
    asm volatile("s_waitcnt vmcnt(0)" ::: "memory");  // tile-i loads landed (flew during compute(i-1))
    __builtin_amdgcn_s_barrier();
    if (i + 1 < n2) stage((i + 1) & 1, s0 + i + 1);
    const char* kbase0 = (const char*)Ks[g2][i & 1];
    const char* vbase0 = (const char*)Vs[g2][i & 1];
    // ---- QK^T both sets (K fragments shared): lane = one q, regs = keys ----
    f32x16 sA[2] = {}, sB[2] = {};
    #pragma unroll
    for (int kt = 0; kt < 2; ++kt) {
      const char* kbase = kbase0 + kt * 4096 + pk32 * 128;
      int kswz = (pk32 & 7) << 4;
      #pragma unroll
      for (int dt = 0; dt < 4; ++dt) {
        bf16x8 kf = *(const bf16x8*)(kbase + ((dt * 32 + hh * 16) ^ kswz));
        sA[kt] = mfma32(kf, qfA[dt], sA[kt]);
        sB[kt] = mfma32(kf, qfB[dt], sB[kt]);
      }
    }
    // ---- no-max exp2 softmax both sets; PV shares V fragments ----
    #pragma unroll
    for (int kt = 0; kt < 2; ++kt) {
      #pragma unroll
      for (int r = 0; r < 16; ++r) sA[kt][r] = EXP2(sA[kt][r]);
      #pragma unroll
      for (int r = 0; r < 16; ++r) sB[kt][r] = EXP2(sB[kt][r]);
      lA += (((sA[kt][0] + sA[kt][1]) + (sA[kt][2] + sA[kt][3])) + ((sA[kt][4] + sA[kt][5]) + (sA[kt][6] + sA[kt][7]))) +
            (((sA[kt][8] + sA[kt][9]) + (sA[kt][10] + sA[kt][11])) + ((sA[kt][12] + sA[kt][13]) + (sA[kt][14] + sA[kt][15])));
      lB += (((sB[kt][0] + sB[kt][1]) + (sB[kt][2] + sB[kt][3])) + ((sB[kt][4] + sB[kt][5]) + (sB[kt][6] + sB[kt][7]))) +
            (((sB[kt][8] + sB[kt][9]) + (sB[kt][10] + sB[kt][11])) + ((sB[kt][12] + sB[kt][13]) + (sB[kt][14] + sB[kt][15])));
      u32 wA[8], wB[8];
      #pragma unroll
      for (int j = 0; j < 8; ++j) wA[j] = cvtpk(sA[kt][2 * j], sA[kt][2 * j + 1]);
      #pragma unroll
      for (int j = 0; j < 8; ++j) wB[j] = cvtpk(sB[kt][2 * j], sB[kt][2 * j + 1]);
      bf16x8 pbA0 = mk_frag(wA[0], wA[1], wA[2], wA[3]);
      bf16x8 pbA1 = mk_frag(wA[4], wA[5], wA[6], wA[7]);
      bf16x8 pbB0 = mk_frag(wB[0], wB[1], wB[2], wB[3]);
      bf16x8 pbB1 = mk_frag(wB[4], wB[5], wB[6], wB[7]);
      int vswz = (q32 & 7) << 4;
      #pragma unroll
      for (int dtv = 0; dtv < 2; ++dtv) {
        const char* vbase = vbase0 + dtv * 4096 + q32 * 128;
        bf16x8 va0 = *(const bf16x8*)(vbase + ((kt * 64 + hh * 16) ^ vswz));
        accA[dtv] = mfma32(va0, pbA0, accA[dtv]);
        accB[dtv] = mfma32(va0, pbB0, accB[dtv]);
        bf16x8 va1 = *(const bf16x8*)(vbase + ((kt * 64 + 32 + hh * 16) ^ vswz));
        accA[dtv] = mfma32(va1, pbA1, accA[dtv]);
        accB[dtv] = mfma32(va1, pbB1, accB[dtv]);
      }
    }
  }

  // ---- merge: group 1 hands (acc, l) to group 0 via LDS ----
  __syncthreads();
  char* M = (char*)&Ks[0][0][0];                    // 32 KB: acc exchange, [wq][set] regions
  float* Lx = (float*)((char*)&Vs[0][0][0] + 24576);// 1 KB: l exchange
  if (g2 == 1) {
    #pragma unroll
    for (int set = 0; set < 2; ++set) {
      const f32x16* ac = set ? accB : accA;
      #pragma unroll
      for (int dtv = 0; dtv < 2; ++dtv)
        #pragma unroll
        for (int j = 0; j < 4; ++j) {
          f32x4 chunk = {ac[dtv][4 * j], ac[dtv][4 * j + 1], ac[dtv][4 * j + 2], ac[dtv][4 * j + 3]};
          int byte = lane * 128 + dtv * 64 + j * 16;
          *(f32x4*)(M + wq * 16384 + set * 8192 + (byte ^ ((lane & 7) << 4))) = chunk;
        }
      Lx[(wq * 2 + set) * 64 + lane] = set ? lB : lA;
    }
  }
  __syncthreads();
  if (g2 == 0) {
    #pragma unroll
    for (int set = 0; set < 2; ++set) {
      f32x16* ac = set ? accB : accA;
      #pragma unroll
      for (int dtv = 0; dtv < 2; ++dtv)
        #pragma unroll
        for (int j = 0; j < 4; ++j) {
          int byte = lane * 128 + dtv * 64 + j * 16;
          f32x4 chunk = *(const f32x4*)(M + wq * 16384 + set * 8192 + (byte ^ ((lane & 7) << 4)));
          #pragma unroll
          for (int e = 0; e < 4; ++e) ac[dtv][4 * j + e] += chunk[e];
        }
      float l = (set ? lB : lA) + Lx[(wq * 2 + set) * 64 + lane];
      l += __shfl_xor(l, 32);
      float rl = 1.0f / l;
      // epilogue: O^T -> per-wave 4 KB LDS region -> row-major vector store
      char* Ow = (char*)&Vs[0][0][0] + wq * 4096;
      #pragma unroll
      for (int dtv = 0; dtv < 2; ++dtv)
        #pragma unroll
        for (int j = 0; j < 4; ++j) {
          int d = dtv * 32 + 8 * j + 4 * hh;
          uint2 wp;
          wp.x = cvtpk(ac[dtv][4 * j] * rl, ac[dtv][4 * j + 1] * rl);
          wp.y = cvtpk(ac[dtv][4 * j + 2] * rl, ac[dtv][4 * j + 3] * rl);
          *(uint2*)(Ow + q32 * 128 + ((d * 2) ^ ((q32 & 7) << 4))) = wp;
        }
      asm volatile("s_waitcnt lgkmcnt(0)" ::: "memory");
      __builtin_amdgcn_sched_barrier(0);
      #pragma unroll
      for (int rep = 0; rep < 4; ++rep) {
        int q = lane >> 1, dblk = (lane & 1) * 4 + rep, d0 = dblk * 8;
        bf16x8 ov = *(const bf16x8*)(Ow + q * 128 + ((d0 * 2) ^ ((q & 7) << 4)));
        *(bf16x8*)(ctx + (size_t)(q0 + set * 32 + q) * 1024 + hd * 64 + d0) = ov;
      }
      asm volatile("s_waitcnt lgkmcnt(0) vmcnt(0)" ::: "memory");  // region reuse between sets
      __builtin_amdgcn_sched_barrier(0);
    }
  }
}

extern "C" void kernel_launch(void* const* d_in, const int* in_sizes, int n_in,
                              void* d_out, int out_size, void* d_ws, size_t ws_size,
                              hipStream_t stream) {
  const float* q   = (const float*)d_in[0];
  const float* kv  = (const float*)d_in[1];
  const float* Wq  = (const float*)d_in[2];
  const float* Wkv = (const float*)d_in[3];
  const float* Wo  = (const float*)d_in[4];
  char* ws = (char*)d_ws;
  u16* qbf  = (u16*)(ws);                // 8 MB   cvt_tw -> gemm_qkv
  u16* ctx  = (u16*)(ws);                // 8 MB   attn -> gemm_out (over dead qbf)
  u16* kvbf = (u16*)(ws + 8388608);      // 8 MB   cvt_tw -> gemm_qkv
  u16* qp   = (u16*)(ws + 16777216);     // 8 MB   gemm_qkv -> attn
  u16* kvp  = (u16*)(ws + 25165824);     // 512 KB gemm_qkv -> attn (K, [4096][64])
  u16* vtg  = (u16*)(ws + 25690112);     // 512 KB gemm_qkv -> attn (V^T, [64][4096])
  u16* wqt  = (u16*)(ws + 26214400);     // 2 MB
  u16* wkvt = (u16*)(ws + 28311552);     // 256 KB
  u16* wot  = (u16*)(ws + 28573696);     // 2 MB
  cvt_tw<<<4640, 256, 0, stream>>>(q, kv, Wq, Wkv, Wo, qbf, wqt, wkvt, wot);
  gemm_qkv<<<576, 256, 0, stream>>>(qbf, kvbf, wqt, wkvt, qp, kvp, vtg);
  attn_kernel<<<512, 256, 0, stream>>>(qp, kvp, vtg, ctx);
  gemm_bt<0><<<512, 256, 0, stream>>>(ctx, wot, (float*)d_out, 1024, 1024, 1.0f);
}